// Round 1
// baseline (37.190 us; speedup 1.0000x reference)
//
#include <hip/hip_runtime.h>

// PaddedMasking: out[b,c,h,w] = x[b,c,h,w] * mask(h,w)
// mask(h,w) = patch_vals[(h-6)/18, (w-6)/18] if (h-6)%18<12 && (w-6)%18<12
//             && h-6,w-6 in [0, 378), else 1.0f
// x: (64,3,384,384) fp32.  Memory-bound: 113 MB in + 113 MB out.

#define IMG    384
#define PAD    6
#define STRIDE 18
#define PATCH  12
#define NP     21
#define SPAN   (NP * STRIDE)   // 378

__global__ __launch_bounds__(256) void padded_mask_mul(
    const float* __restrict__ x,
    const int*   __restrict__ pv,
    float*       __restrict__ out,
    int n4)
{
    int idx = blockIdx.x * blockDim.x + threadIdx.x;
    if (idx >= n4) return;

    int pixel = idx << 2;                 // flat element index (float)
    int w0 = pixel % IMG;                 // 0..380, multiple of 4
    int h  = (pixel / IMG) % IMG;         // row within plane (all 4 lanes share h)

    // row-side patch test (branchless, unsigned trick folds the h<6 case)
    unsigned urh = (unsigned)(h - PAD);
    unsigned rq  = urh / (unsigned)STRIDE;            // magic-mul
    bool row_ok  = (urh < (unsigned)SPAN) & ((urh - rq * STRIDE) < (unsigned)PATCH);

    float4 v = *reinterpret_cast<const float4*>(x + (size_t)pixel);

    float m[4];
#pragma unroll
    for (int j = 0; j < 4; ++j) {
        unsigned ucw = (unsigned)(w0 + j - PAD);
        unsigned cq  = ucw / (unsigned)STRIDE;
        bool col_ok  = (ucw < (unsigned)SPAN) & ((ucw - cq * STRIDE) < (unsigned)PATCH);
        bool ok      = row_ok & col_ok;
        int  pidx    = ok ? (int)(rq * NP + cq) : 0;  // clamp: no OOB load
        float pval   = (float)pv[pidx];               // L1-resident 1.7 KB table
        m[j] = ok ? pval : 1.0f;
    }

    float4 o;
    o.x = v.x * m[0];
    o.y = v.y * m[1];
    o.z = v.z * m[2];
    o.w = v.w * m[3];
    *reinterpret_cast<float4*>(out + (size_t)pixel) = o;
}

extern "C" void kernel_launch(void* const* d_in, const int* in_sizes, int n_in,
                              void* d_out, int out_size, void* d_ws, size_t ws_size,
                              hipStream_t stream)
{
    const float* x  = (const float*)d_in[0];
    const int*   pv = (const int*)d_in[1];
    float*       out = (float*)d_out;

    int n4 = out_size >> 2;               // 28,311,552 / 4 = 7,077,888
    int blocks = (n4 + 255) / 256;        // 27,648
    padded_mask_mul<<<blocks, 256, 0, stream>>>(x, pv, out, n4);
}